// Round 1
// baseline (97.991 us; speedup 1.0000x reference)
//
#include <hip/hip_runtime.h>

// GRNN_3547642986522: B=4096 sequential filters over T=2048.
// Decomposition: cov/f/t evolve independently of dy & x; x is linear given cov.
// K1: per (b, segment s): warm up cov from t=0 (redundant, latency-bound),
//     write segment-start checkpoint, accumulate 2x2 transfer (X) and offset (Q)
//     over the segment's 128 steps (reads dy staged via LDS).
// K2: per (b, s): fold X/Q of earlier segments to get x at segment start,
//     replay 128 steps emitting dy_hat (staged via LDS, coalesced f4 stores).
//     s==15 threads write nstate and fnew.
// ws layout: PQ planes [6][S][B] then CP planes [6][S][B] -> 3 MiB needed.

#define NBATCH 4096
#define NT     2048
#define NSEG   16
#define LSEG   128   // NT / NSEG
#define CHT    32    // timesteps per LDS chunk
#define NCHK   4     // LSEG / CHT
#define LDSW   36    // 32 data floats + 4 pad (f4 stride 9, odd -> conflict-free b128)
#define ROWF4  1024  // float4 per dy row (NT*2/4)

namespace gk {

constexpr float DT   = 0.001f;
constexpr float A00  = -0.15f;       // -GAMMA/2
constexpr float A01  = 6.283185f;    //  OMEGA
constexpr float A10  = -6.283185f;
constexpr float A11  = -0.15f;
constexpr float C0   = 1.6970562748477141f;  // sqrt(4*ETA*KAPPA)
constexpr float DD   = 5.25f;        // GAMMA*(N_TH+0.5)+KAPPA

constexpr float P00c = 1.0f + DT*A00;
constexpr float P01c = DT*A01;
constexpr float P10c = DT*A10;
constexpr float P11c = 1.0f + DT*A11;
constexpr float DTC  = DT*C0;
constexpr float cVA  = 1.0f + 2.0f*DT*A00;
constexpr float cVB  = 2.0f*DT*A01;
constexpr float cVBn = 2.0f*DT*A10;
constexpr float cVD  = DT*DD;
constexpr float cCA  = 1.0f + DT*(A00+A11);
constexpr float cCB  = DT*A10;
constexpr float cCC  = DT*A01;
constexpr float YC   = C0*DT;

// One step of the deterministic part (cov, f, t). Returns pre-update xi0/xi1
// (xicov column 0) and the updated f0 (reference uses fnew in dx).
__device__ __forceinline__ void covf_step(
    float& vx, float& vp, float& cxp, float& f0, float& f1, float& t,
    float k00, float k01, float k10, float k11,
    float& xi0o, float& xi1o, float& nf0o)
{
    float xi0 = C0*vx, xi1 = C0*cxp;
    float nf0 = fmaf(DT, fmaf(k00, f0, k01*f1), f0);
    float nf1 = fmaf(DT, fmaf(k10, f0, k11*f1), f1);
    float nvx = fmaf(-DT, xi0*xi0, fmaf(cVA, vx,  fmaf(cVB,  cxp, cVD)));
    float nvp = fmaf(-DT, xi1*xi1, fmaf(cVA, vp,  fmaf(cVBn, cxp, cVD)));
    float ncx = fmaf(-DT, xi0*xi1, fmaf(cCA, cxp, fmaf(cCB,  vx,  cCC*vp)));
    vx = nvx; vp = nvp; cxp = ncx; f0 = nf0; f1 = nf1; t += DT;
    xi0o = xi0; xi1o = xi1; nf0o = nf0;
}

__device__ __forceinline__ float f4c(const float4& q, int c) {
    return c==0 ? q.x : c==1 ? q.y : c==2 ? q.z : q.w;
}

// Cooperative load of one chunk: 64 rows x 16 f4 (2 timesteps, both channels).
// Lane l: p = l&15 (f4 within row-quarter), rows rl+4i. One wave instruction
// covers 4 rows x 16 consecutive f4 = 4 x 256B coalesced segments.
__device__ __forceinline__ void issue_loads(float4* stg, const float4* dy4,
                                            int b0, int s, int c, int lane)
{
    const int p = lane & 15, rl = lane >> 4;
    const float4* base = dy4 + (size_t)(b0 + rl) * ROWF4 + s*64 + c*16 + p;
    #pragma unroll
    for (int i = 0; i < 16; ++i)
        stg[i] = base[(size_t)i * 4 * ROWF4];
}

} // namespace gk

extern "C" __global__ void __launch_bounds__(64)
k1_summary(const float* __restrict__ dy, const float* __restrict__ state,
           const float* __restrict__ fin, const float* __restrict__ kp,
           float* __restrict__ ws)
{
    using namespace gk;
    __shared__ float ibuf[2][64][LDSW];
    const int lane = threadIdx.x;
    const int b0   = blockIdx.x * 64;
    const int s    = blockIdx.y;
    const int b    = b0 + lane;

    const float k00 = kp[0], k01 = kp[1], k10 = kp[2], k11 = kp[3];
    float vx  = state[b*6+2], vp = state[b*6+3], cxp = state[b*6+4];
    float t   = state[b*6+5];
    float f0  = fin[b*2+0],   f1 = fin[b*2+1];

    const float4* dy4 = reinterpret_cast<const float4*>(dy);
    float4 stg[16];
    issue_loads(stg, dy4, b0, s, 0, lane);   // chunk 0 in flight during warmup

    // Warm the deterministic state up to this segment's start.
    const int nwarm = s * LSEG;
    float d0, d1, d2;
    #pragma unroll 4
    for (int it = 0; it < nwarm; ++it)
        covf_step(vx, vp, cxp, f0, f1, t, k00, k01, k10, k11, d0, d1, d2);

    // Segment-start checkpoint (planes [6][S][B], coalesced in b).
    float* PQ = ws;
    float* CP = ws + 6*NSEG*NBATCH;
    const int sb = s*NBATCH + b;
    CP[0*NSEG*NBATCH + sb] = vx;
    CP[1*NSEG*NBATCH + sb] = vp;
    CP[2*NSEG*NBATCH + sb] = cxp;
    CP[3*NSEG*NBATCH + sb] = f0;
    CP[4*NSEG*NBATCH + sb] = f1;
    CP[5*NSEG*NBATCH + sb] = t;

    float X00 = 1.f, X01 = 0.f, X10 = 0.f, X11 = 1.f, Q0 = 0.f, Q1 = 0.f;
    const int p = lane & 15, rl = lane >> 4;

    for (int c = 0; c < NCHK; ++c) {
        const int cb = c & 1;
        #pragma unroll
        for (int i = 0; i < 16; ++i) {           // extract ch0 into LDS tile
            int row = 4*i + rl;
            *reinterpret_cast<float2*>(&ibuf[cb][row][2*p]) =
                make_float2(stg[i].x, stg[i].z);
        }
        if (c < NCHK-1) issue_loads(stg, dy4, b0, s, c+1, lane); // depth-1 prefetch
        // Wave-local LDS drain only (no vmcnt(0): keep prefetch in flight).
        asm volatile("s_waitcnt lgkmcnt(0)" ::: "memory");
        __builtin_amdgcn_sched_barrier(0);

        float4 v[8];
        #pragma unroll
        for (int i = 0; i < 8; ++i)
            v[i] = *reinterpret_cast<const float4*>(&ibuf[cb][lane][4*i]);

        #pragma unroll
        for (int i = 0; i < CHT; ++i) {
            float dy0 = f4c(v[i>>2], i & 3);
            float xi0, xi1, nf0;
            covf_step(vx, vp, cxp, f0, f1, t, k00, k01, k10, k11, xi0, xi1, nf0);
            float p00 = fmaf(-DTC, xi0, P00c);
            float p10 = fmaf(-DTC, xi1, P10c);
            float r0  = xi0*dy0;
            float r1  = fmaf(DT, nf0, xi1*dy0);
            float nX00 = fmaf(p00, X00, P01c*X10);
            float nX01 = fmaf(p00, X01, P01c*X11);
            float nX10 = fmaf(p10, X00, P11c*X10);
            float nX11 = fmaf(p10, X01, P11c*X11);
            float nQ0  = fmaf(p00, Q0, fmaf(P01c, Q1, r0));
            float nQ1  = fmaf(p10, Q0, fmaf(P11c, Q1, r1));
            X00 = nX00; X01 = nX01; X10 = nX10; X11 = nX11; Q0 = nQ0; Q1 = nQ1;
        }
    }

    PQ[0*NSEG*NBATCH + sb] = X00;
    PQ[1*NSEG*NBATCH + sb] = X01;
    PQ[2*NSEG*NBATCH + sb] = X10;
    PQ[3*NSEG*NBATCH + sb] = X11;
    PQ[4*NSEG*NBATCH + sb] = Q0;
    PQ[5*NSEG*NBATCH + sb] = Q1;
}

extern "C" __global__ void __launch_bounds__(64)
k2_replay(const float* __restrict__ dy, const float* __restrict__ state,
          const float* __restrict__ kp, const float* __restrict__ ws,
          float* __restrict__ out)
{
    using namespace gk;
    __shared__ float ibuf[2][64][LDSW];
    __shared__ float obuf[2][64][LDSW];
    const int lane = threadIdx.x;
    const int b0   = blockIdx.x * 64;
    const int s    = blockIdx.y;
    const int b    = b0 + lane;

    const float k00 = kp[0], k01 = kp[1], k10 = kp[2], k11 = kp[3];

    const float4* dy4 = reinterpret_cast<const float4*>(dy);
    float4 stg[16];
    issue_loads(stg, dy4, b0, s, 0, lane);   // overlap fold latency

    const float* PQ = ws;
    const float* CP = ws + 6*NSEG*NBATCH;
    const int sb = s*NBATCH + b;
    float vx  = CP[0*NSEG*NBATCH + sb];
    float vp  = CP[1*NSEG*NBATCH + sb];
    float cxp = CP[2*NSEG*NBATCH + sb];
    float f0  = CP[3*NSEG*NBATCH + sb];
    float f1  = CP[4*NSEG*NBATCH + sb];
    float t   = CP[5*NSEG*NBATCH + sb];

    // x at segment start: fold earlier segments' (X, Q).
    float x0 = state[b*6+0], x1 = state[b*6+1];
    for (int s2 = 0; s2 < s; ++s2) {
        const int sb2 = s2*NBATCH + b;
        float X00 = PQ[0*NSEG*NBATCH + sb2];
        float X01 = PQ[1*NSEG*NBATCH + sb2];
        float X10 = PQ[2*NSEG*NBATCH + sb2];
        float X11 = PQ[3*NSEG*NBATCH + sb2];
        float Q0  = PQ[4*NSEG*NBATCH + sb2];
        float Q1  = PQ[5*NSEG*NBATCH + sb2];
        float nx0 = fmaf(X00, x0, fmaf(X01, x1, Q0));
        float nx1 = fmaf(X10, x0, fmaf(X11, x1, Q1));
        x0 = nx0; x1 = nx1;
    }

    float4* dh4 = reinterpret_cast<float4*>(out + 6*NBATCH);
    const int p = lane & 15, rl = lane >> 4;

    for (int c = 0; c < NCHK; ++c) {
        const int cb = c & 1;
        #pragma unroll
        for (int i = 0; i < 16; ++i) {
            int row = 4*i + rl;
            *reinterpret_cast<float2*>(&ibuf[cb][row][2*p]) =
                make_float2(stg[i].x, stg[i].z);
        }
        if (c < NCHK-1) issue_loads(stg, dy4, b0, s, c+1, lane);
        asm volatile("s_waitcnt lgkmcnt(0)" ::: "memory");
        __builtin_amdgcn_sched_barrier(0);

        float4 v[8];
        #pragma unroll
        for (int i = 0; i < 8; ++i)
            v[i] = *reinterpret_cast<const float4*>(&ibuf[cb][lane][4*i]);

        float yh0 = 0.f;
        #pragma unroll
        for (int i = 0; i < CHT; ++i) {
            float dy0 = f4c(v[i>>2], i & 3);
            float yh  = YC * x0;              // dy_hat uses pre-update x
            if (i & 1) {
                *reinterpret_cast<float2*>(&obuf[cb][lane][i-1]) =
                    make_float2(yh0, yh);
            } else {
                yh0 = yh;
            }
            float xi0, xi1, nf0;
            covf_step(vx, vp, cxp, f0, f1, t, k00, k01, k10, k11, xi0, xi1, nf0);
            float p00 = fmaf(-DTC, xi0, P00c);
            float p10 = fmaf(-DTC, xi1, P10c);
            float r0  = xi0*dy0;
            float r1  = fmaf(DT, nf0, xi1*dy0);
            float nx0 = fmaf(p00, x0, fmaf(P01c, x1, r0));
            float nx1 = fmaf(p10, x0, fmaf(P11c, x1, r1));
            x0 = nx0; x1 = nx1;
        }
        asm volatile("s_waitcnt lgkmcnt(0)" ::: "memory");
        __builtin_amdgcn_sched_barrier(0);

        #pragma unroll
        for (int i = 0; i < 16; ++i) {        // coalesced f4 stores {yh,0,yh',0}
            int row = 4*i + rl;
            float2 v2 = *reinterpret_cast<const float2*>(&obuf[cb][row][2*p]);
            dh4[(size_t)(b0+row)*ROWF4 + s*64 + c*16 + p] =
                make_float4(v2.x, 0.f, v2.y, 0.f);
        }
    }

    if (s == NSEG-1) {
        out[b*6+0] = x0; out[b*6+1] = x1;
        out[b*6+2] = vx; out[b*6+3] = vp; out[b*6+4] = cxp; out[b*6+5] = t;
        float* fo = out + 6*NBATCH + (size_t)NBATCH*NT*2;
        fo[b*2+0] = f0; fo[b*2+1] = f1;
    }
}

extern "C" void kernel_launch(void* const* d_in, const int* in_sizes, int n_in,
                              void* d_out, int out_size, void* d_ws, size_t ws_size,
                              hipStream_t stream)
{
    const float* dy    = (const float*)d_in[0];
    const float* state = (const float*)d_in[1];
    const float* fin   = (const float*)d_in[2];
    const float* kp    = (const float*)d_in[3];
    float* out = (float*)d_out;
    float* ws  = (float*)d_ws;   // needs 12*NSEG*NBATCH*4 = 3 MiB

    dim3 grid(NBATCH/64, NSEG);
    dim3 blk(64);
    hipLaunchKernelGGL(k1_summary, grid, blk, 0, stream, dy, state, fin, kp, ws);
    hipLaunchKernelGGL(k2_replay,  grid, blk, 0, stream, dy, state, kp, ws, out);
}

// Round 2
// 82.107 us; speedup vs baseline: 1.1935x; 1.1935x over previous
//
#include <hip/hip_runtime.h>

// GRNN_3547642986522: B=4096 sequential filters over T=2048.
// cov (Riccati) is the only irreducibly serial chain; x is linear given cov;
// f is linear-constant; t is closed-form.
// K0: B threads walk cov 2048 steps (lean 10-op step), checkpoint every 128.
//     f checkpoints via M128 = (I+dt K)^128 (7 squarings).
// K1: per (b,s in 0..14): start from checkpoint, 128 steps accumulating 2x2
//     transfer X and offset Q (reads dy staged via LDS).
// K2: per (b,s in 0..15): fold X/Q of earlier segments -> x at segment start,
//     replay 128 steps emitting dy_hat. s==15 writes nstate & fnew.
// ws: PQ [6][16][B] then CP [5][16][B] -> 2.88 MiB.

#define NBATCH 4096
#define NT     2048
#define NSEG   16
#define LSEG   128
#define CHT    32
#define NCHK   4
#define LDSW   36    // 32 data floats + 4 pad
#define ROWF4  1024  // float4 per dy row
#define PLANE  (NSEG*NBATCH)

namespace gk {

constexpr float DT   = 0.001f;
constexpr float A00  = -0.15f;
constexpr float A01  = 6.283185f;
constexpr float A10  = -6.283185f;
constexpr float A11  = -0.15f;
constexpr float C0   = 1.6970562748477141f;  // sqrt(4*ETA*KAPPA)
constexpr float DD   = 5.25f;                // GAMMA*(N_TH+0.5)+KAPPA

constexpr float P00c = 1.0f + DT*A00;
constexpr float P01c = DT*A01;
constexpr float P10c = DT*A10;
constexpr float P11c = 1.0f + DT*A11;
constexpr float DTC  = DT*C0;
constexpr float QQ   = DT*C0*C0;             // dt*C0^2
constexpr float cVA  = 1.0f + 2.0f*DT*A00;
constexpr float cVB  = 2.0f*DT*A01;
constexpr float cVBn = 2.0f*DT*A10;
constexpr float cVD  = DT*DD;
constexpr float cCA  = 1.0f + DT*(A00+A11);
constexpr float cCB  = DT*A10;
constexpr float cCC  = DT*A01;
constexpr float YC   = C0*DT;

// Lean cov step: 10 VALU ops, dep depth 3.
//   nvx = (cVA - QQ*vx)*vx + (cVB*cxp + cVD)
//   nvp = cVA*vp + ((cVBn - QQ*cxp)*cxp + cVD)
//   ncx = (cCA - QQ*vx)*cxp + (cCB*vx + cCC*vp)
__device__ __forceinline__ void cov_step(float& vx, float& vp, float& cxp)
{
    float a1 = fmaf(-QQ, vx,  cVA);
    float b1 = fmaf(cVB, cxp, cVD);
    float a2 = fmaf(-QQ, cxp, cVBn);
    float b2 = fmaf(a2,  cxp, cVD);
    float a3 = fmaf(-QQ, vx,  cCA);
    float m  = cCC * vp;
    float c3 = fmaf(cCB, vx,  m);
    float nvx = fmaf(a1,  vx,  b1);
    float nvp = fmaf(cVA, vp,  b2);
    float ncx = fmaf(a3,  cxp, c3);
    vx = nvx; vp = nvp; cxp = ncx;
}

// Full step for K1/K2 main loops (cov + f), returns pre-update xi0/xi1, new f0.
__device__ __forceinline__ void covf_step(
    float& vx, float& vp, float& cxp, float& f0, float& f1,
    float k00, float k01, float k10, float k11,
    float& xi0o, float& xi1o, float& nf0o)
{
    float xi0 = C0*vx, xi1 = C0*cxp;
    float nf0 = fmaf(DT, fmaf(k00, f0, k01*f1), f0);
    float nf1 = fmaf(DT, fmaf(k10, f0, k11*f1), f1);
    xi0o = xi0; xi1o = xi1; nf0o = nf0;
    cov_step(vx, vp, cxp);
    f0 = nf0; f1 = nf1;
}

__device__ __forceinline__ float f4c(const float4& q, int c) {
    return c==0 ? q.x : c==1 ? q.y : c==2 ? q.z : q.w;
}

// Cooperative load of one chunk: 64 rows x 16 f4 (32 timesteps, both channels).
__device__ __forceinline__ void issue_loads(float4* stg, const float4* dy4,
                                            int b0, int s, int c, int lane)
{
    const int p = lane & 15, rl = lane >> 4;
    const float4* base = dy4 + (size_t)(b0 + rl) * ROWF4 + s*64 + c*16 + p;
    #pragma unroll
    for (int i = 0; i < 16; ++i)
        stg[i] = base[(size_t)i * 4 * ROWF4];
}

} // namespace gk

// ---------------------------------------------------------------- K0
extern "C" __global__ void __launch_bounds__(64)
k0_checkpoint(const float* __restrict__ state, const float* __restrict__ fin,
              const float* __restrict__ kp, float* __restrict__ ws)
{
    using namespace gk;
    const int b = blockIdx.x*64 + threadIdx.x;
    float vx  = state[b*6+2], vp = state[b*6+3], cxp = state[b*6+4];
    float f0  = fin[b*2+0],   f1 = fin[b*2+1];

    // M128 = (I + dt*K)^128 via 7 squarings (uniform, trivial cost).
    float m00 = fmaf(DT, kp[0], 1.0f), m01 = DT*kp[1];
    float m10 = DT*kp[2],              m11 = fmaf(DT, kp[3], 1.0f);
    #pragma unroll
    for (int i = 0; i < 7; ++i) {
        float a = fmaf(m00,m00, m01*m10);
        float q = fmaf(m00,m01, m01*m11);
        float c = fmaf(m10,m00, m11*m10);
        float d = fmaf(m10,m01, m11*m11);
        m00=a; m01=q; m10=c; m11=d;
    }

    float* CP = ws + 6*PLANE;
    #pragma unroll 1
    for (int s = 0; s < NSEG; ++s) {
        const int sb = s*NBATCH + b;
        CP[0*PLANE+sb] = vx;  CP[1*PLANE+sb] = vp;  CP[2*PLANE+sb] = cxp;
        CP[3*PLANE+sb] = f0;  CP[4*PLANE+sb] = f1;
        if (s == NSEG-1) break;
        float nf0 = fmaf(m00, f0, m01*f1);
        float nf1 = fmaf(m10, f0, m11*f1);
        f0 = nf0; f1 = nf1;
        #pragma unroll 16
        for (int k = 0; k < LSEG; ++k) cov_step(vx, vp, cxp);
    }
}

// ---------------------------------------------------------------- K1
extern "C" __global__ void __launch_bounds__(64)
k1_xq(const float* __restrict__ dy, const float* __restrict__ kp,
      const float* __restrict__ ws_in, float* __restrict__ ws)
{
    using namespace gk;
    __shared__ float ibuf[2][64][LDSW];
    const int lane = threadIdx.x;
    const int b0   = blockIdx.x * 64;
    const int s    = blockIdx.y;          // 0..14
    const int b    = b0 + lane;

    const float k00 = kp[0], k01 = kp[1], k10 = kp[2], k11 = kp[3];

    const float4* dy4 = reinterpret_cast<const float4*>(dy);
    float4 stg[16];
    issue_loads(stg, dy4, b0, s, 0, lane);

    const float* CP = ws_in + 6*PLANE;
    const int sb = s*NBATCH + b;
    float vx  = CP[0*PLANE+sb], vp = CP[1*PLANE+sb], cxp = CP[2*PLANE+sb];
    float f0  = CP[3*PLANE+sb], f1 = CP[4*PLANE+sb];

    float X00 = 1.f, X01 = 0.f, X10 = 0.f, X11 = 1.f, Q0 = 0.f, Q1 = 0.f;
    const int p = lane & 15, rl = lane >> 4;

    for (int c = 0; c < NCHK; ++c) {
        const int cb = c & 1;
        #pragma unroll
        for (int i = 0; i < 16; ++i) {
            int row = 4*i + rl;
            *reinterpret_cast<float2*>(&ibuf[cb][row][2*p]) =
                make_float2(stg[i].x, stg[i].z);
        }
        if (c < NCHK-1) issue_loads(stg, dy4, b0, s, c+1, lane);
        asm volatile("s_waitcnt lgkmcnt(0)" ::: "memory");
        __builtin_amdgcn_sched_barrier(0);

        float4 v[8];
        #pragma unroll
        for (int i = 0; i < 8; ++i)
            v[i] = *reinterpret_cast<const float4*>(&ibuf[cb][lane][4*i]);

        #pragma unroll
        for (int i = 0; i < CHT; ++i) {
            float dy0 = f4c(v[i>>2], i & 3);
            float xi0, xi1, nf0;
            covf_step(vx, vp, cxp, f0, f1, k00, k01, k10, k11, xi0, xi1, nf0);
            float p00 = fmaf(-DTC, xi0, P00c);
            float p10 = fmaf(-DTC, xi1, P10c);
            float r0  = xi0*dy0;
            float r1  = fmaf(DT, nf0, xi1*dy0);
            float nX00 = fmaf(p00, X00, P01c*X10);
            float nX01 = fmaf(p00, X01, P01c*X11);
            float nX10 = fmaf(p10, X00, P11c*X10);
            float nX11 = fmaf(p10, X01, P11c*X11);
            float nQ0  = fmaf(p00, Q0, fmaf(P01c, Q1, r0));
            float nQ1  = fmaf(p10, Q0, fmaf(P11c, Q1, r1));
            X00 = nX00; X01 = nX01; X10 = nX10; X11 = nX11; Q0 = nQ0; Q1 = nQ1;
        }
    }

    float* PQ = ws;
    PQ[0*PLANE+sb] = X00;
    PQ[1*PLANE+sb] = X01;
    PQ[2*PLANE+sb] = X10;
    PQ[3*PLANE+sb] = X11;
    PQ[4*PLANE+sb] = Q0;
    PQ[5*PLANE+sb] = Q1;
}

// ---------------------------------------------------------------- K2
extern "C" __global__ void __launch_bounds__(64)
k2_replay(const float* __restrict__ dy, const float* __restrict__ state,
          const float* __restrict__ kp, const float* __restrict__ ws,
          float* __restrict__ out)
{
    using namespace gk;
    __shared__ float ibuf[2][64][LDSW];
    __shared__ float obuf[2][64][LDSW];
    const int lane = threadIdx.x;
    const int b0   = blockIdx.x * 64;
    const int s    = blockIdx.y;          // 0..15
    const int b    = b0 + lane;

    const float k00 = kp[0], k01 = kp[1], k10 = kp[2], k11 = kp[3];

    const float4* dy4 = reinterpret_cast<const float4*>(dy);
    float4 stg[16];
    issue_loads(stg, dy4, b0, s, 0, lane);

    const float* PQ = ws;
    const float* CP = ws + 6*PLANE;
    const int sb = s*NBATCH + b;
    float vx  = CP[0*PLANE+sb], vp = CP[1*PLANE+sb], cxp = CP[2*PLANE+sb];
    float f0  = CP[3*PLANE+sb], f1 = CP[4*PLANE+sb];

    // x at segment start: fold earlier segments' (X, Q).
    float x0 = state[b*6+0], x1 = state[b*6+1];
    for (int s2 = 0; s2 < s; ++s2) {
        const int sb2 = s2*NBATCH + b;
        float X00 = PQ[0*PLANE+sb2], X01 = PQ[1*PLANE+sb2];
        float X10 = PQ[2*PLANE+sb2], X11 = PQ[3*PLANE+sb2];
        float Q0  = PQ[4*PLANE+sb2], Q1  = PQ[5*PLANE+sb2];
        float nx0 = fmaf(X00, x0, fmaf(X01, x1, Q0));
        float nx1 = fmaf(X10, x0, fmaf(X11, x1, Q1));
        x0 = nx0; x1 = nx1;
    }

    float4* dh4 = reinterpret_cast<float4*>(out + 6*NBATCH);
    const int p = lane & 15, rl = lane >> 4;

    for (int c = 0; c < NCHK; ++c) {
        const int cb = c & 1;
        #pragma unroll
        for (int i = 0; i < 16; ++i) {
            int row = 4*i + rl;
            *reinterpret_cast<float2*>(&ibuf[cb][row][2*p]) =
                make_float2(stg[i].x, stg[i].z);
        }
        if (c < NCHK-1) issue_loads(stg, dy4, b0, s, c+1, lane);
        asm volatile("s_waitcnt lgkmcnt(0)" ::: "memory");
        __builtin_amdgcn_sched_barrier(0);

        float4 v[8];
        #pragma unroll
        for (int i = 0; i < 8; ++i)
            v[i] = *reinterpret_cast<const float4*>(&ibuf[cb][lane][4*i]);

        float yh0 = 0.f;
        #pragma unroll
        for (int i = 0; i < CHT; ++i) {
            float dy0 = f4c(v[i>>2], i & 3);
            float yh  = YC * x0;              // dy_hat uses pre-update x
            if (i & 1) {
                *reinterpret_cast<float2*>(&obuf[cb][lane][i-1]) =
                    make_float2(yh0, yh);
            } else {
                yh0 = yh;
            }
            float xi0, xi1, nf0;
            covf_step(vx, vp, cxp, f0, f1, k00, k01, k10, k11, xi0, xi1, nf0);
            float p00 = fmaf(-DTC, xi0, P00c);
            float p10 = fmaf(-DTC, xi1, P10c);
            float r0  = xi0*dy0;
            float r1  = fmaf(DT, nf0, xi1*dy0);
            float nx0 = fmaf(p00, x0, fmaf(P01c, x1, r0));
            float nx1 = fmaf(p10, x0, fmaf(P11c, x1, r1));
            x0 = nx0; x1 = nx1;
        }
        asm volatile("s_waitcnt lgkmcnt(0)" ::: "memory");
        __builtin_amdgcn_sched_barrier(0);

        #pragma unroll
        for (int i = 0; i < 16; ++i) {
            int row = 4*i + rl;
            float2 v2 = *reinterpret_cast<const float2*>(&obuf[cb][row][2*p]);
            dh4[(size_t)(b0+row)*ROWF4 + s*64 + c*16 + p] =
                make_float4(v2.x, 0.f, v2.y, 0.f);
        }
    }

    if (s == NSEG-1) {
        out[b*6+0] = x0; out[b*6+1] = x1;
        out[b*6+2] = vx; out[b*6+3] = vp; out[b*6+4] = cxp;
        out[b*6+5] = state[b*6+5] + 2048.0f*0.001f;   // t: closed form
        float* fo = out + 6*NBATCH + (size_t)NBATCH*NT*2;
        fo[b*2+0] = f0; fo[b*2+1] = f1;
    }
}

extern "C" void kernel_launch(void* const* d_in, const int* in_sizes, int n_in,
                              void* d_out, int out_size, void* d_ws, size_t ws_size,
                              hipStream_t stream)
{
    const float* dy    = (const float*)d_in[0];
    const float* state = (const float*)d_in[1];
    const float* fin   = (const float*)d_in[2];
    const float* kp    = (const float*)d_in[3];
    float* out = (float*)d_out;
    float* ws  = (float*)d_ws;   // 11 planes * 64K * 4B = 2.88 MiB

    hipLaunchKernelGGL(k0_checkpoint, dim3(NBATCH/64), dim3(64), 0, stream,
                       state, fin, kp, ws);
    hipLaunchKernelGGL(k1_xq, dim3(NBATCH/64, NSEG-1), dim3(64), 0, stream,
                       dy, kp, ws, ws);
    hipLaunchKernelGGL(k2_replay, dim3(NBATCH/64, NSEG), dim3(64), 0, stream,
                       dy, state, kp, ws, out);
}

// Round 4
// 54.025 us; speedup vs baseline: 1.8138x; 1.5198x over previous
//
#include <hip/hip_runtime.h>
#include <cmath>

// GRNN_3547642986522 — B=4096 filters, T=2048 steps.
// cov (Riccati) checkpoints via closed-form LFT: the Euler step matches the
// Kalman step P' = AhP(I+CdP)^-1 Ah^T + Qd to O(dt^2); that step is a linear-
// fractional transform whose 4x4 matrix is CONSTANT -> M64 = M^64 computed on
// host in double. Each (b,s) block rebuilds its checkpoint with <=31 LFT
// applications (parallel, ~1us) -- no serial 2048-step walk.
// k1: checkpoint + accumulate per-segment 2x2 transfer X / offset Q; write CP+PQ.
// k2: fold PQ prefix -> x at segment start; replay segment (Euler, exact),
//     emit dy_hat via LDS (in-place), s==S-1 writes nstate & fnew.
// ws: PQ [6][S][B] then CP [5][S][B]. S=32 -> 5.75 MiB (fallback S=16, 2.88 MiB).

#define NBATCH 4096
#define NT     2048
#define ROWF4  1024   // float4 per dy row

struct M16 { float m[16]; };   // LFT matrix [[E,F],[G,H]] row-major 4x4

namespace gk {

constexpr float DT   = 0.001f;
constexpr float A00  = -0.15f;
constexpr float A01  = 6.283185f;
constexpr float A10  = -6.283185f;
constexpr float A11  = -0.15f;
constexpr float C0   = 1.6970562748477141f;
constexpr float DD   = 5.25f;

constexpr float P00c = 1.0f + DT*A00;
constexpr float P01c = DT*A01;
constexpr float P10c = DT*A10;
constexpr float P11c = 1.0f + DT*A11;
constexpr float DTC  = DT*C0;
constexpr float QQ   = DT*C0*C0;
constexpr float cVA  = 1.0f + 2.0f*DT*A00;
constexpr float cVB  = 2.0f*DT*A01;
constexpr float cVBn = 2.0f*DT*A10;
constexpr float cVD  = DT*DD;
constexpr float cCA  = 1.0f + DT*(A00+A11);
constexpr float cCB  = DT*A10;
constexpr float cCC  = DT*A01;
constexpr float YC   = C0*DT;

template<int S>
struct cfg {
    static constexpr int LSEG  = NT / S;
    static constexpr int NCHK  = LSEG / 32;
    static constexpr int LDSW  = LSEG + 4;
    static constexpr int SEGF4 = LSEG / 2;
    static constexpr int PLANE = S * NBATCH;
    static constexpr int LOG2L = (LSEG == 32) ? 5 : (LSEG == 64) ? 6 : 7;
};

__device__ __forceinline__ void cov_step(float& vx, float& vp, float& cxp)
{
    float a1 = fmaf(-QQ, vx,  cVA);
    float b1 = fmaf(cVB, cxp, cVD);
    float a2 = fmaf(-QQ, cxp, cVBn);
    float b2 = fmaf(a2,  cxp, cVD);
    float a3 = fmaf(-QQ, vx,  cCA);
    float m  = cCC * vp;
    float c3 = fmaf(cCB, vx,  m);
    float nvx = fmaf(a1,  vx,  b1);
    float nvp = fmaf(cVA, vp,  b2);
    float ncx = fmaf(a3,  cxp, c3);
    vx = nvx; vp = nvp; cxp = ncx;
}

__device__ __forceinline__ void covf_step(
    float& vx, float& vp, float& cxp, float& f0, float& f1,
    float k00, float k01, float k10, float k11,
    float& xi0o, float& xi1o, float& nf0o)
{
    float xi0 = C0*vx, xi1 = C0*cxp;
    float nf0 = fmaf(DT, fmaf(k00, f0, k01*f1), f0);
    float nf1 = fmaf(DT, fmaf(k10, f0, k11*f1), f1);
    xi0o = xi0; xi1o = xi1; nf0o = nf0;
    cov_step(vx, vp, cxp);
    f0 = nf0; f1 = nf1;
}

// One LFT application: P -> (E P + F)(G P + H)^-1, P = [[vx,cxp],[cxp,vp]].
__device__ __forceinline__ void lft_apply(const M16& mc, float& vx, float& vp, float& cxp)
{
    const float* m = mc.m;
    float n00 = fmaf(m[0], vx,  fmaf(m[1], cxp, m[2]));
    float n01 = fmaf(m[0], cxp, fmaf(m[1], vp,  m[3]));
    float n10 = fmaf(m[4], vx,  fmaf(m[5], cxp, m[6]));
    float n11 = fmaf(m[4], cxp, fmaf(m[5], vp,  m[7]));
    float d00 = fmaf(m[8],  vx,  fmaf(m[9],  cxp, m[10]));
    float d01 = fmaf(m[8],  cxp, fmaf(m[9],  vp,  m[11]));
    float d10 = fmaf(m[12], vx,  fmaf(m[13], cxp, m[14]));
    float d11 = fmaf(m[12], cxp, fmaf(m[13], vp,  m[15]));
    float rdet = 1.0f / fmaf(d00, d11, -d01*d10);
    float p00 = fmaf(n00, d11, -n01*d10) * rdet;
    float p01 = fmaf(n01, d00, -n00*d01) * rdet;
    float p10 = fmaf(n10, d11, -n11*d10) * rdet;
    float p11 = fmaf(n11, d00, -n10*d01) * rdet;
    vx = p00; vp = p11; cxp = 0.5f*(p01 + p10);
}

__device__ __forceinline__ float f4c(const float4& q, int c) {
    return c==0 ? q.x : c==1 ? q.y : c==2 ? q.z : q.w;
}
__device__ __forceinline__ void f4set(float4& q, int c, float v) {
    if (c==0) q.x=v; else if (c==1) q.y=v; else if (c==2) q.z=v; else q.w=v;
}

template<int S>
__device__ __forceinline__ void issue_loads(float4* stg, const float4* dy4,
                                            int b0, int s, int c, int lane)
{
    const int p = lane & 15, rl = lane >> 4;
    const float4* base = dy4 + (size_t)(b0 + rl) * ROWF4
                       + s*cfg<S>::SEGF4 + c*16 + p;
    #pragma unroll
    for (int i = 0; i < 16; ++i)
        stg[i] = base[(size_t)i * 4 * ROWF4];
}

} // namespace gk

// ---------------------------------------------------------------- k1
template<int S>
__global__ void __launch_bounds__(64, 2)
k1_xq(const float* __restrict__ dy, const float* __restrict__ state,
      const float* __restrict__ fin, const float* __restrict__ kp,
      M16 mc, float* __restrict__ ws)
{
    using namespace gk;
    constexpr int NCHK = cfg<S>::NCHK, LDSW = cfg<S>::LDSW, PLANE = cfg<S>::PLANE;
    __shared__ float lds[64][LDSW];
    const int lane = threadIdx.x;
    const int b0   = blockIdx.x * 64, s = blockIdx.y, b = b0 + lane;
    const int p    = lane & 15, rl = lane >> 4;
    const float k00 = kp[0], k01 = kp[1], k10 = kp[2], k11 = kp[3];

    const float4* dy4 = reinterpret_cast<const float4*>(dy);
    float4 stg[16];
    issue_loads<S>(stg, dy4, b0, s, 0, lane);   // overlap checkpoint compute

    float vx = state[b*6+2], vp = state[b*6+3], cxp = state[b*6+4];
    float f0 = fin[b*2+0],   f1 = fin[b*2+1];

    // Mf = (I + dt K)^LSEG
    float mf00 = fmaf(DT,k00,1.f), mf01 = DT*k01;
    float mf10 = DT*k10,           mf11 = fmaf(DT,k11,1.f);
    #pragma unroll
    for (int i = 0; i < cfg<S>::LOG2L; ++i) {
        float a = fmaf(mf00,mf00, mf01*mf10);
        float q = fmaf(mf00,mf01, mf01*mf11);
        float c = fmaf(mf10,mf00, mf11*mf10);
        float d = fmaf(mf10,mf01, mf11*mf11);
        mf00=a; mf01=q; mf10=c; mf11=d;
    }

    // Checkpoint: s LFT applications (cov) + s matrix applications (f).
    #pragma unroll 1
    for (int i = 0; i < s; ++i) {
        lft_apply(mc, vx, vp, cxp);
        float nf0 = fmaf(mf00, f0, mf01*f1);
        float nf1 = fmaf(mf10, f0, mf11*f1);
        f0 = nf0; f1 = nf1;
    }

    float* PQ = ws;
    float* CP = ws + 6*PLANE;
    const int sb = s*NBATCH + b;
    CP[0*PLANE+sb] = vx;  CP[1*PLANE+sb] = vp;  CP[2*PLANE+sb] = cxp;
    CP[3*PLANE+sb] = f0;  CP[4*PLANE+sb] = f1;

    float X00 = 1.f, X01 = 0.f, X10 = 0.f, X11 = 1.f, Q0 = 0.f, Q1 = 0.f;

    #pragma unroll 1
    for (int c = 0; c < NCHK; ++c) {
        #pragma unroll
        for (int i = 0; i < 16; ++i) {
            int row = 4*i + rl;
            *reinterpret_cast<float2*>(&lds[row][c*32 + 2*p]) =
                make_float2(stg[i].x, stg[i].z);
        }
        if (c < NCHK-1) issue_loads<S>(stg, dy4, b0, s, c+1, lane);
        asm volatile("s_waitcnt lgkmcnt(0)" ::: "memory");
        __builtin_amdgcn_sched_barrier(0);

        float4 v[8];
        #pragma unroll
        for (int i = 0; i < 8; ++i)
            v[i] = *reinterpret_cast<const float4*>(&lds[lane][c*32 + 4*i]);

        #pragma unroll
        for (int i = 0; i < 32; ++i) {
            float dy0 = f4c(v[i>>2], i & 3);
            float xi0, xi1, nf0;
            covf_step(vx, vp, cxp, f0, f1, k00, k01, k10, k11, xi0, xi1, nf0);
            float p00 = fmaf(-DTC, xi0, P00c);
            float p10 = fmaf(-DTC, xi1, P10c);
            float r0  = xi0*dy0;
            float r1  = fmaf(DT, nf0, xi1*dy0);
            float nX00 = fmaf(p00, X00, P01c*X10);
            float nX01 = fmaf(p00, X01, P01c*X11);
            float nX10 = fmaf(p10, X00, P11c*X10);
            float nX11 = fmaf(p10, X01, P11c*X11);
            float nQ0  = fmaf(p00, Q0, fmaf(P01c, Q1, r0));
            float nQ1  = fmaf(p10, Q0, fmaf(P11c, Q1, r1));
            X00 = nX00; X01 = nX01; X10 = nX10; X11 = nX11; Q0 = nQ0; Q1 = nQ1;
        }
    }

    PQ[0*PLANE+sb] = X00;  PQ[1*PLANE+sb] = X01;
    PQ[2*PLANE+sb] = X10;  PQ[3*PLANE+sb] = X11;
    PQ[4*PLANE+sb] = Q0;   PQ[5*PLANE+sb] = Q1;
}

// ---------------------------------------------------------------- k2
template<int S>
__global__ void __launch_bounds__(64, 2)
k2_replay(const float* __restrict__ dy, const float* __restrict__ state,
          const float* __restrict__ kp, const float* __restrict__ ws,
          float* __restrict__ out)
{
    using namespace gk;
    constexpr int NCHK = cfg<S>::NCHK, LDSW = cfg<S>::LDSW, PLANE = cfg<S>::PLANE;
    __shared__ float lds[64][LDSW];
    const int lane = threadIdx.x;
    const int b0   = blockIdx.x * 64, s = blockIdx.y, b = b0 + lane;
    const int p    = lane & 15, rl = lane >> 4;
    const float k00 = kp[0], k01 = kp[1], k10 = kp[2], k11 = kp[3];

    const float4* dy4 = reinterpret_cast<const float4*>(dy);
    float4 stg[16];
    issue_loads<S>(stg, dy4, b0, s, 0, lane);   // overlap fold latency

    const float* PQ = ws;
    const float* CP = ws + 6*PLANE;
    const int sb = s*NBATCH + b;
    float vx = CP[0*PLANE+sb], vp = CP[1*PLANE+sb], cxp = CP[2*PLANE+sb];
    float f0 = CP[3*PLANE+sb], f1 = CP[4*PLANE+sb];

    float x0 = state[b*6+0], x1 = state[b*6+1];
    #pragma unroll 1
    for (int s2 = 0; s2 < s; ++s2) {
        const int q = s2*NBATCH + b;
        float Y00 = PQ[0*PLANE+q], Y01 = PQ[1*PLANE+q];
        float Y10 = PQ[2*PLANE+q], Y11 = PQ[3*PLANE+q];
        float R0  = PQ[4*PLANE+q], R1  = PQ[5*PLANE+q];
        float nx0 = fmaf(Y00, x0, fmaf(Y01, x1, R0));
        float nx1 = fmaf(Y10, x0, fmaf(Y11, x1, R1));
        x0 = nx0; x1 = nx1;
    }

    float4* dh4 = reinterpret_cast<float4*>(out + 6*NBATCH);

    #pragma unroll 1
    for (int c = 0; c < NCHK; ++c) {
        #pragma unroll
        for (int i = 0; i < 16; ++i) {
            int row = 4*i + rl;
            *reinterpret_cast<float2*>(&lds[row][c*32 + 2*p]) =
                make_float2(stg[i].x, stg[i].z);
        }
        if (c < NCHK-1) issue_loads<S>(stg, dy4, b0, s, c+1, lane);
        asm volatile("s_waitcnt lgkmcnt(0)" ::: "memory");
        __builtin_amdgcn_sched_barrier(0);

        float4 v[8];
        #pragma unroll
        for (int i = 0; i < 8; ++i)
            v[i] = *reinterpret_cast<const float4*>(&lds[lane][c*32 + 4*i]);

        #pragma unroll
        for (int i = 0; i < 32; ++i) {
            float dy0 = f4c(v[i>>2], i & 3);
            float yh  = YC * x0;              // pre-update x
            f4set(v[i>>2], i & 3, yh);
            float xi0, xi1, nf0;
            covf_step(vx, vp, cxp, f0, f1, k00, k01, k10, k11, xi0, xi1, nf0);
            float p00 = fmaf(-DTC, xi0, P00c);
            float p10 = fmaf(-DTC, xi1, P10c);
            float r0  = xi0*dy0;
            float r1  = fmaf(DT, nf0, xi1*dy0);
            float nx0 = fmaf(p00, x0, fmaf(P01c, x1, r0));
            float nx1 = fmaf(p10, x0, fmaf(P11c, x1, r1));
            x0 = nx0; x1 = nx1;
        }
        #pragma unroll
        for (int i = 0; i < 8; ++i)
            *reinterpret_cast<float4*>(&lds[lane][c*32 + 4*i]) = v[i];
        asm volatile("s_waitcnt lgkmcnt(0)" ::: "memory");
        __builtin_amdgcn_sched_barrier(0);

        #pragma unroll
        for (int i = 0; i < 16; ++i) {
            int row = 4*i + rl;
            float2 v2 = *reinterpret_cast<const float2*>(&lds[row][c*32 + 2*p]);
            dh4[(size_t)(b0+row)*ROWF4 + s*cfg<S>::SEGF4 + c*16 + p] =
                make_float4(v2.x, 0.f, v2.y, 0.f);
        }
    }

    if (s == S-1) {
        out[b*6+0] = x0; out[b*6+1] = x1;
        out[b*6+2] = vx; out[b*6+3] = vp; out[b*6+4] = cxp;
        out[b*6+5] = state[b*6+5] + 2.048f;
        float* fo = out + 6*NBATCH + (size_t)NBATCH*NT*2;
        fo[b*2+0] = f0; fo[b*2+1] = f1;
    }
}

// Host: M_step = [[E,F],[G,H]] for the Kalman LFT step; return M_step^LSEG.
static M16 build_m_pow(int log2l)
{
    const double dt = 0.001;
    const double a00 = -0.15, a01 = 6.283185, a10 = -6.283185, a11 = -0.15;
    const double c0c0 = 4.0 * 0.8 * 0.9;            // C0^2
    const double qq = dt * c0c0;                    // Cd = diag(qq,0)
    const double qd = dt * (0.3*14.5 + 0.9);        // dt*DD = dt*5.25
    const double h00 = 1.0 + dt*a00, h01 = dt*a01;
    const double h10 = dt*a10,       h11 = 1.0 + dt*a11;
    const double det = h00*h11 - h01*h10;
    // AinvT = [[h11,-h10],[-h01,h00]]/det
    const double t00 = h11/det, t01 = -h10/det, t10 = -h01/det, t11 = h00/det;
    const double g00 = t00*qq, g10 = t10*qq;        // G = AinvT*Cd
    double M[4][4] = {
        { h00 + qd*g00, h01,           qd*t00, qd*t01 },
        { h10 + qd*g10, h11,           qd*t10, qd*t11 },
        { g00,          0.0,           t00,    t01    },
        { g10,          0.0,           t10,    t11    },
    };
    for (int it = 0; it < log2l; ++it) {
        double R[4][4];
        for (int i = 0; i < 4; ++i)
            for (int j = 0; j < 4; ++j) {
                double acc = 0.0;
                for (int k = 0; k < 4; ++k) acc += M[i][k]*M[k][j];
                R[i][j] = acc;
            }
        for (int i = 0; i < 4; ++i)
            for (int j = 0; j < 4; ++j) M[i][j] = R[i][j];
    }
    M16 r;
    for (int i = 0; i < 4; ++i)
        for (int j = 0; j < 4; ++j) r.m[i*4+j] = (float)M[i][j];
    return r;
}

extern "C" void kernel_launch(void* const* d_in, const int* in_sizes, int n_in,
                              void* d_out, int out_size, void* d_ws, size_t ws_size,
                              hipStream_t stream)
{
    const float* dy    = (const float*)d_in[0];
    const float* state = (const float*)d_in[1];
    const float* fin   = (const float*)d_in[2];
    const float* kp    = (const float*)d_in[3];
    float* out = (float*)d_out;
    float* ws  = (float*)d_ws;

    const size_t need32 = (size_t)11 * 32 * NBATCH * sizeof(float);  // 5.75 MiB
    if (ws_size >= need32) {
        M16 mc = build_m_pow(6);   // LSEG = 64
        k1_xq<32><<<dim3(NBATCH/64, 32), dim3(64), 0, stream>>>(dy, state, fin, kp, mc, ws);
        k2_replay<32><<<dim3(NBATCH/64, 32), dim3(64), 0, stream>>>(dy, state, kp, ws, out);
    } else {
        M16 mc = build_m_pow(7);   // LSEG = 128
        k1_xq<16><<<dim3(NBATCH/64, 16), dim3(64), 0, stream>>>(dy, state, fin, kp, mc, ws);
        k2_replay<16><<<dim3(NBATCH/64, 16), dim3(64), 0, stream>>>(dy, state, kp, ws, out);
    }
}